// Round 8
// baseline (330.649 us; speedup 1.0000x reference)
//
#include <hip/hip_runtime.h>
#include <hip/hip_cooperative_groups.h>

namespace cg = cooperative_groups;

// Problem constants (from reference setup_inputs): B=4, N=4096, D=128.
constexpr int BATCH = 4;
constexpr int N = 4096;
constexpr int D = 128;
constexpr int J4 = N / 4;             // 1024 float4s per output row
constexpr int RPB = 8;                // rows of out per block (R6 best: 8)

typedef float vfloat4 __attribute__((ext_vector_type(4)));

__device__ __forceinline__ float dot4(const vfloat4 a, const vfloat4 b) {
    return a.x * b.x + a.y * b.y + a.z * b.z + a.w * b.w;
}

// ---------------------------------------------------------------------------
// Fused cooperative kernel, 2048 blocks x 256 (exactly 8 blocks/CU co-resident).
// Phase A: block p computes dots for ITS rows [8p, 8p+8): threads 0..127 in
//   16-lane groups, 2 coalesced float4 loads/lane, 4-step butterfly.
//   a-dots -> LDS (block-local use only); b-dots -> global Bv.
// grid.sync(): makes all Bv visible (device-scope fence included).
// Phase B: identical to the proven R6 outer loop (RPB=8, plain stores --
//   R4 A/B showed plain beats nontemporal; R7 showed RPB=32 regresses).
// ---------------------------------------------------------------------------
__global__ __launch_bounds__(256, 8)
void fused_kernel(const float* __restrict__ E,
                  const float* __restrict__ W,
                  float* __restrict__ Bv,
                  vfloat4* __restrict__ out) {
    __shared__ float a_lds[RPB];
    const int p     = blockIdx.x;
    const int row0  = p * RPB;
    const int batch = row0 >> 12;
    const int t     = threadIdx.x;

    // ---- Phase A ----
    if (t < 128) {
        const int g = t >> 4;            // 0..7 -> row within block
        const int s = t & 15;            // float4 slot within row
        const int row = row0 + g;
        const float* rp = E + (size_t)row * D;
        const vfloat4 e1  = *reinterpret_cast<const vfloat4*>(rp + s * 4);
        const vfloat4 e2  = *reinterpret_cast<const vfloat4*>(rp + 64 + s * 4);
        const vfloat4 wi1 = *reinterpret_cast<const vfloat4*>(W + s * 4);
        const vfloat4 wi2 = *reinterpret_cast<const vfloat4*>(W + 64 + s * 4);
        const vfloat4 wj1 = *reinterpret_cast<const vfloat4*>(W + D + s * 4);
        const vfloat4 wj2 = *reinterpret_cast<const vfloat4*>(W + D + 64 + s * 4);

        float pa = dot4(e1, wi1) + dot4(e2, wi2);
        float pb = dot4(e1, wj1) + dot4(e2, wj2);
        #pragma unroll
        for (int off = 8; off >= 1; off >>= 1) {
            pa += __shfl_xor(pa, off);
            pb += __shfl_xor(pb, off);
        }
        if (s == 0) {
            a_lds[g] = pa;
            Bv[row]  = pb;
        }
    }
    __threadfence();
    cg::this_grid().sync();              // Bv from all blocks now visible

    // ---- Phase B ----
    const vfloat4* __restrict__ bv4 =
        reinterpret_cast<const vfloat4*>(Bv) + (size_t)batch * J4;

    float a[RPB];
    #pragma unroll
    for (int r = 0; r < RPB; ++r) a[r] = a_lds[r];

    #pragma unroll
    for (int k = 0; k < J4 / 256; ++k) {                // 4 iterations
        const int j4 = t + k * 256;
        const vfloat4 b4 = bv4[j4];
        #pragma unroll
        for (int r = 0; r < RPB; ++r) {
            out[(size_t)(row0 + r) * J4 + j4] = b4 + a[r];
        }
    }
}

// ---------------------------------------------------------------------------
// Fallback path (two kernels, R6 structure) if cooperative launch fails.
// ---------------------------------------------------------------------------
__global__ __launch_bounds__(256)
void dots_kernel(const float* __restrict__ E,
                 const float* __restrict__ W,
                 float* __restrict__ A,
                 float* __restrict__ Bv) {
    const int gtid = blockIdx.x * blockDim.x + threadIdx.x;
    const int wave = gtid >> 6;
    const int g    = (threadIdx.x >> 4) & 3;
    const int s    = threadIdx.x & 15;
    const int row  = wave * 4 + g;

    const float* rp = E + (size_t)row * D;
    const vfloat4 e1  = *reinterpret_cast<const vfloat4*>(rp + s * 4);
    const vfloat4 e2  = *reinterpret_cast<const vfloat4*>(rp + 64 + s * 4);
    const vfloat4 wi1 = *reinterpret_cast<const vfloat4*>(W + s * 4);
    const vfloat4 wi2 = *reinterpret_cast<const vfloat4*>(W + 64 + s * 4);
    const vfloat4 wj1 = *reinterpret_cast<const vfloat4*>(W + D + s * 4);
    const vfloat4 wj2 = *reinterpret_cast<const vfloat4*>(W + D + 64 + s * 4);

    float pa = dot4(e1, wi1) + dot4(e2, wi2);
    float pb = dot4(e1, wj1) + dot4(e2, wj2);
    #pragma unroll
    for (int off = 8; off >= 1; off >>= 1) {
        pa += __shfl_xor(pa, off);
        pb += __shfl_xor(pb, off);
    }
    if (s == 0) { A[row] = pa; Bv[row] = pb; }
}

__global__ __launch_bounds__(256)
void outer_kernel(const float* __restrict__ A,
                  const float* __restrict__ Bv,
                  vfloat4* __restrict__ out) {
    const int row0  = blockIdx.x * RPB;
    const int batch = row0 >> 12;
    const vfloat4* __restrict__ bv4 =
        reinterpret_cast<const vfloat4*>(Bv) + (size_t)batch * J4;

    float a[RPB];
    #pragma unroll
    for (int r = 0; r < RPB; ++r) a[r] = A[row0 + r];

    #pragma unroll
    for (int k = 0; k < J4 / 256; ++k) {
        const int j4 = threadIdx.x + k * 256;
        const vfloat4 b4 = bv4[j4];
        #pragma unroll
        for (int r = 0; r < RPB; ++r) {
            out[(size_t)(row0 + r) * J4 + j4] = b4 + a[r];
        }
    }
}

extern "C" void kernel_launch(void* const* d_in, const int* in_sizes, int n_in,
                              void* d_out, int out_size, void* d_ws, size_t ws_size,
                              hipStream_t stream) {
    const float* E = (const float*)d_in[0];   // (4, 4096, 128) f32
    const float* W = (const float*)d_in[1];   // (1, 256) f32

    // workspace: Bv (16384 f32) then A (16384 f32, fallback only) = 128 KB
    float* Bv = (float*)d_ws;
    float* A  = Bv + (size_t)BATCH * N;
    vfloat4* out = (vfloat4*)d_out;

    void* args[] = { (void*)&E, (void*)&W, (void*)&Bv, (void*)&out };
    hipError_t err = hipLaunchCooperativeKernel(
        (const void*)fused_kernel,
        dim3((BATCH * N) / RPB),      // 2048 blocks
        dim3(256), args, 0, stream);

    if (err != hipSuccess) {
        // two-kernel fallback (R6 structure)
        dots_kernel<<<(BATCH * N) / 16, 256, 0, stream>>>(E, W, A, Bv);
        outer_kernel<<<(BATCH * N) / RPB, 256, 0, stream>>>(A, Bv, out);
    }
}

// Round 9
// 49.523 us; speedup vs baseline: 6.6766x; 6.6766x over previous
//
#include <hip/hip_runtime.h>

// Problem constants (from reference setup_inputs): B=4, N=4096, D=128.
constexpr int BATCH = 4;
constexpr int N = 4096;
constexpr int D = 128;
constexpr int J4 = N / 4;             // 1024 float4s per output row
constexpr int RPB = 8;                // rows per row-group (R6 best; R7: 32 regresses)
constexpr int NGRP = (BATCH * N) / RPB;  // 2048 row-groups

typedef float vfloat4 __attribute__((ext_vector_type(4)));

__device__ __forceinline__ float dot4(const vfloat4 a, const vfloat4 b) {
    return a.x * b.x + a.y * b.y + a.z * b.z + a.w * b.w;
}

// ---------------------------------------------------------------------------
// Kernel 1: per-row dual dot products (v3, unchanged since R6).
// Wave handles 4 rows via 16-lane groups; two coalesced float4 loads/lane;
// 4-step butterfly reduce within 16 lanes.
// ---------------------------------------------------------------------------
__global__ __launch_bounds__(256)
void dots_kernel(const float* __restrict__ E,
                 const float* __restrict__ W,
                 float* __restrict__ A,
                 float* __restrict__ Bv) {
    const int gtid = blockIdx.x * blockDim.x + threadIdx.x;
    const int wave = gtid >> 6;          // 0..4095
    const int g    = (threadIdx.x >> 4) & 3;
    const int s    = threadIdx.x & 15;
    const int row  = wave * 4 + g;       // exact fit: 4096*4 = 16384 rows

    const float* rp = E + (size_t)row * D;
    const vfloat4 e1  = *reinterpret_cast<const vfloat4*>(rp + s * 4);
    const vfloat4 e2  = *reinterpret_cast<const vfloat4*>(rp + 64 + s * 4);
    const vfloat4 wi1 = *reinterpret_cast<const vfloat4*>(W + s * 4);
    const vfloat4 wi2 = *reinterpret_cast<const vfloat4*>(W + 64 + s * 4);
    const vfloat4 wj1 = *reinterpret_cast<const vfloat4*>(W + D + s * 4);
    const vfloat4 wj2 = *reinterpret_cast<const vfloat4*>(W + D + 64 + s * 4);

    float pa = dot4(e1, wi1) + dot4(e2, wi2);
    float pb = dot4(e1, wj1) + dot4(e2, wj2);

    #pragma unroll
    for (int off = 8; off >= 1; off >>= 1) {
        pa += __shfl_xor(pa, off);
        pb += __shfl_xor(pb, off);
    }
    if (s == 0) {
        A[row]  = pa;
        Bv[row] = pb;
    }
}

// ---------------------------------------------------------------------------
// Kernel 2: outer-sum materialization (write-bound, 268 MB).
//   out[row][j] = A[row] + Bv[(row>>12)*N + j]
// GRID-STRIDE this round (A/B vs R6's one-group-per-block): 1024 blocks,
// each processes 2 row-groups of RPB=8 sequentially. Inner body identical
// to R6 (8 open row-streams, a[] hoisted, Bv float4 reused 8x, plain
// stores). Tests whether short block lifetime / turnover was costing BW.
// ---------------------------------------------------------------------------
__global__ __launch_bounds__(256)
void outer_kernel(const float* __restrict__ A,
                  const float* __restrict__ Bv,
                  vfloat4* __restrict__ out) {
    for (int grp = blockIdx.x; grp < NGRP; grp += gridDim.x) {
        const int row0  = grp * RPB;
        const int batch = row0 >> 12;                   // row / 4096
        const vfloat4* __restrict__ bv4 =
            reinterpret_cast<const vfloat4*>(Bv) + (size_t)batch * J4;

        float a[RPB];
        #pragma unroll
        for (int r = 0; r < RPB; ++r) a[r] = A[row0 + r];

        #pragma unroll
        for (int k = 0; k < J4 / 256; ++k) {            // 4 iterations
            const int j4 = threadIdx.x + k * 256;
            const vfloat4 b4 = bv4[j4];
            #pragma unroll
            for (int r = 0; r < RPB; ++r) {
                out[(size_t)(row0 + r) * J4 + j4] = b4 + a[r];
            }
        }
    }
}

extern "C" void kernel_launch(void* const* d_in, const int* in_sizes, int n_in,
                              void* d_out, int out_size, void* d_ws, size_t ws_size,
                              hipStream_t stream) {
    const float* E = (const float*)d_in[0];   // (4, 4096, 128) f32
    const float* W = (const float*)d_in[1];   // (1, 256) f32

    // workspace: A (16384 f32) then Bv (16384 f32) = 128 KB
    float* A  = (float*)d_ws;
    float* Bv = A + (size_t)BATCH * N;

    // Kernel 1: 16384 rows, 4 rows/wave, 16 rows/block -> 1024 blocks
    dots_kernel<<<(BATCH * N) / 16, 256, 0, stream>>>(E, W, A, Bv);

    // Kernel 2: 1024 long-lived blocks, 2 row-groups each (grid-stride)
    outer_kernel<<<1024, 256, 0, stream>>>(A, Bv, (vfloat4*)d_out);
}